// Round 2
// baseline (380.001 us; speedup 1.0000x reference)
//
#include <hip/hip_runtime.h>
#include <hip/hip_bf16.h>

// LSTM: S=128, N=2048, H=128, O=128. All buffers fp32 (per reference dtypes).
// Internally bf16 MFMA. One persistent kernel: 128 blocks x 512 threads; block b
// owns samples [16b,16b+16). Recurrence is row-independent => no grid sync.
// Weights live in VGPRs as bf16 fragments.

#define S_LEN   128
#define N_BATCH 2048
#define H_DIM   128
#define O_DIM   128

using short8  = __attribute__((ext_vector_type(8))) short;  // 8 bf16 (4 VGPRs)
using floatx4 = __attribute__((ext_vector_type(4))) float;  // 4 fp32 acc
typedef unsigned short u16;

#define ROWP     264                 // LDS row pitch in bf16 elems (256 + 8 pad)
#define BUFELEMS (16 * ROWP)         // one A-tile buffer: 16 rows

__device__ __forceinline__ u16 f2b(float f) {   // RNE f32->bf16
    unsigned int u = __float_as_uint(f);
    return (u16)((u + 0x7FFF + ((u >> 16) & 1)) >> 16);
}
__device__ __forceinline__ short8 pack8(const float* p) {
    short8 r;
#pragma unroll
    for (int i = 0; i < 8; ++i) r[i] = (short)f2b(p[i]);
    return r;
}
__device__ __forceinline__ float sigmoidf_fast(float v) {
    return __builtin_amdgcn_rcpf(1.0f + __builtin_amdgcn_exp2f(-1.4426950408889634f * v));
}
__device__ __forceinline__ float tanhf_fast(float v) {
    return 1.0f - 2.0f * __builtin_amdgcn_rcpf(1.0f + __builtin_amdgcn_exp2f(2.8853900817779268f * v));
}

__global__ __launch_bounds__(512, 2)
void lstm_persist(const float* __restrict__ x,
                  const float* __restrict__ W_ih,
                  const float* __restrict__ W_hh,
                  const float* __restrict__ b_ih,
                  const float* __restrict__ b_hh,
                  const float* __restrict__ W_out,
                  const float* __restrict__ b_out,
                  float* __restrict__ pred) {
    __shared__ short sh[2 * BUFELEMS];   // double-buffered [x_t | h_{t-1}] tile, 16x256 (+pad)

    const int tid  = (int)threadIdx.x;
    const int wave = tid >> 6;           // 0..7
    const int lane = tid & 63;
    const int quad = lane >> 4;          // 0..3
    const int l15  = lane & 15;
    const int n0   = (int)blockIdx.x * 16;

    // ---- load weights into bf16 register fragments ----
    // B-frag layout (16x16x32): lane holds B[k=quad*8+j][n=l15].
    // wave w owns gate j-slice [w*16, w*16+16): tile t = gate type (i,f,g,o),
    // gate row g = t*128 + w*16 + l15.  K = [x(0:128) | h(128:256)].
    short8 wg[4][8];
    float  biasv[4];
#pragma unroll
    for (int t = 0; t < 4; ++t) {
        const int g = t * 128 + wave * 16 + l15;
#pragma unroll
        for (int kk = 0; kk < 4; ++kk)
            wg[t][kk] = pack8(W_ih + g * H_DIM + kk * 32 + quad * 8);
#pragma unroll
        for (int kk = 4; kk < 8; ++kk)
            wg[t][kk] = pack8(W_hh + g * H_DIM + (kk - 4) * 32 + quad * 8);
        biasv[t] = b_ih[g] + b_hh[g];
    }
    short8 wo[4];
    const int ocol = wave * 16 + l15;
#pragma unroll
    for (int kk = 0; kk < 4; ++kk)
        wo[kk] = pack8(W_out + ocol * H_DIM + kk * 32 + quad * 8);
    const float bo = b_out[ocol];

    // ---- prologue: zero h region of buf0, stage x_0 into buf0.x ----
    for (int i = tid; i < 16 * 128; i += 512)
        sh[(i >> 7) * ROWP + 128 + (i & 127)] = 0;

    const int  xm = tid >> 4;            // row within tile (valid for tid<256)
    const int  xc = (tid & 15) * 8;      // col (8 elems per thread)
    const bool isLoader = (tid < 256);
    if (isLoader) {
        const float* p = x + ((size_t)(n0 + xm)) * H_DIM + xc;
        float4 f0 = *reinterpret_cast<const float4*>(p);
        float4 f1 = *reinterpret_cast<const float4*>(p + 4);
        float tmp[8] = {f0.x, f0.y, f0.z, f0.w, f1.x, f1.y, f1.z, f1.w};
        *reinterpret_cast<short8*>(&sh[xm * ROWP + xc]) = pack8(tmp);
    }

    float cc[4] = {0.f, 0.f, 0.f, 0.f};  // cell state: c[m=quad*4+r][j=wave*16+l15]
    __syncthreads();

    const int arow = l15 * ROWP + quad * 8;   // a-frag base: A[m=l15][k=quad*8+..]
    const int hcol = 128 + wave * 16 + l15;   // where this lane's h goes in LDS

    // ---- main recurrence ----
    for (int s = 0; s < S_LEN; ++s) {
        short* shb = sh + (s & 1) * BUFELEMS;        // holds [x_s | h_{s-1}]
        short* shn = sh + ((s & 1) ^ 1) * BUFELEMS;  // will hold [x_{s+1} | h_s]

        // prefetch x_{s+1} (fp32 -> bf16 later)
        float4 xr0, xr1;
        const bool doLoad = isLoader && (s + 1 < S_LEN);
        if (doLoad) {
            const float* p = x + ((size_t)(s + 1) * N_BATCH + n0 + xm) * H_DIM + xc;
            xr0 = *reinterpret_cast<const float4*>(p);
            xr1 = *reinterpret_cast<const float4*>(p + 4);
        }

        floatx4 acc0 = {biasv[0], biasv[0], biasv[0], biasv[0]};
        floatx4 acc1 = {biasv[1], biasv[1], biasv[1], biasv[1]};
        floatx4 acc2 = {biasv[2], biasv[2], biasv[2], biasv[2]};
        floatx4 acc3 = {biasv[3], biasv[3], biasv[3], biasv[3]};
        floatx4 ao   = {bo, bo, bo, bo};             // out-proj for h_{s-1}

#pragma unroll
        for (int kk = 0; kk < 8; ++kk) {
            short8 a = *reinterpret_cast<const short8*>(&shb[arow + kk * 32]);
            acc0 = __builtin_amdgcn_mfma_f32_16x16x32_bf16(a, wg[0][kk], acc0, 0, 0, 0);
            acc1 = __builtin_amdgcn_mfma_f32_16x16x32_bf16(a, wg[1][kk], acc1, 0, 0, 0);
            acc2 = __builtin_amdgcn_mfma_f32_16x16x32_bf16(a, wg[2][kk], acc2, 0, 0, 0);
            acc3 = __builtin_amdgcn_mfma_f32_16x16x32_bf16(a, wg[3][kk], acc3, 0, 0, 0);
            if (kk >= 4)  // h part doubles as out-proj A operand
                ao = __builtin_amdgcn_mfma_f32_16x16x32_bf16(a, wo[kk - 4], ao, 0, 0, 0);
        }

        // store pred_{s-1} (pipelined one step behind), fp32
        if (s > 0) {
            size_t base = ((size_t)(s - 1) * N_BATCH + n0 + quad * 4) * O_DIM + wave * 16 + l15;
#pragma unroll
            for (int r = 0; r < 4; ++r)
                pred[base + (size_t)r * O_DIM] = ao[r];
        }

        // activations + state update (D layout: row m = quad*4+r, col j = wave*16+l15)
        float hv[4];
#pragma unroll
        for (int r = 0; r < 4; ++r) {
            float iv = sigmoidf_fast(acc0[r]);
            float fv = sigmoidf_fast(acc1[r]);
            float gv = tanhf_fast(acc2[r]);
            float ov = sigmoidf_fast(acc3[r]);
            cc[r] = fv * cc[r] + iv * gv;
            hv[r] = ov * tanhf_fast(cc[r]);
        }

        // stage next A-tile: x_{s+1} and h_s into the other buffer
        if (doLoad) {
            float tmp[8] = {xr0.x, xr0.y, xr0.z, xr0.w, xr1.x, xr1.y, xr1.z, xr1.w};
            *reinterpret_cast<short8*>(&shn[xm * ROWP + xc]) = pack8(tmp);
        }
#pragma unroll
        for (int r = 0; r < 4; ++r)
            shn[(quad * 4 + r) * ROWP + hcol] = (short)f2b(hv[r]);

        __syncthreads();
    }

    // ---- epilogue: pred_{S-1} from h_{127} (sits in buffer 0) ----
    floatx4 ao = {bo, bo, bo, bo};
#pragma unroll
    for (int kk = 4; kk < 8; ++kk) {
        short8 a = *reinterpret_cast<const short8*>(&sh[arow + kk * 32]);
        ao = __builtin_amdgcn_mfma_f32_16x16x32_bf16(a, wo[kk - 4], ao, 0, 0, 0);
    }
    size_t base = ((size_t)(S_LEN - 1) * N_BATCH + n0 + quad * 4) * O_DIM + wave * 16 + l15;
#pragma unroll
    for (int r = 0; r < 4; ++r)
        pred[base + (size_t)r * O_DIM] = ao[r];
}

extern "C" void kernel_launch(void* const* d_in, const int* in_sizes, int n_in,
                              void* d_out, int out_size, void* d_ws, size_t ws_size,
                              hipStream_t stream) {
    const float* x    = (const float*)d_in[0];
    const float* Wih  = (const float*)d_in[1];
    const float* Whh  = (const float*)d_in[2];
    const float* bih  = (const float*)d_in[3];
    const float* bhh  = (const float*)d_in[4];
    const float* Wout = (const float*)d_in[5];
    const float* bout = (const float*)d_in[6];
    float* pred = (float*)d_out;

    lstm_persist<<<dim3(N_BATCH / 16), dim3(512), 0, stream>>>(
        x, Wih, Whh, bih, bhh, Wout, bout, pred);
}

// Round 3
// 359.912 us; speedup vs baseline: 1.0558x; 1.0558x over previous
//
#include <hip/hip_runtime.h>
#include <hip/hip_bf16.h>

// LSTM: S=128, N=2048, H=128, O=128. fp32 buffers, bf16 MFMA internally.
// 128 persistent blocks x 512 threads; block b owns samples [16b,16b+16).
// Critical-path-minimized recurrence:
//   - xg_{s+1} = x_{s+1} W_ih^T computed DURING step s (off the serial chain)
//   - serial chain per step: ds_read h -> 4-deep MFMA (K=128) -> activations
//     -> h write -> barrier
//   - x global loads issued 3 steps ahead of consumption (HBM latency hidden)

#define S_LEN   128
#define N_BATCH 2048
#define H_DIM   128
#define O_DIM   128

using short8  = __attribute__((ext_vector_type(8))) short;  // 8 bf16 (4 VGPRs)
using short4v = __attribute__((ext_vector_type(4))) short;  // 4 bf16
using floatx4 = __attribute__((ext_vector_type(4))) float;  // 4 fp32 acc
typedef unsigned short u16;

#define ROWP     264                 // LDS row pitch in bf16 elems (256 + 8 pad)
#define BUFELEMS (16 * ROWP)         // one tile buffer: 16 rows x [x(0:128)|h(128:256)]

__device__ __forceinline__ u16 f2b(float f) {   // RNE f32->bf16
    unsigned int u = __float_as_uint(f);
    return (u16)((u + 0x7FFF + ((u >> 16) & 1)) >> 16);
}
__device__ __forceinline__ short8 pack8(const float* p) {
    short8 r;
#pragma unroll
    for (int i = 0; i < 8; ++i) r[i] = (short)f2b(p[i]);
    return r;
}
__device__ __forceinline__ short4v pack4(float4 f) {
    short4v r;
    r[0] = (short)f2b(f.x); r[1] = (short)f2b(f.y);
    r[2] = (short)f2b(f.z); r[3] = (short)f2b(f.w);
    return r;
}
__device__ __forceinline__ float sigmoidf_fast(float v) {
    return __builtin_amdgcn_rcpf(1.0f + __builtin_amdgcn_exp2f(-1.4426950408889634f * v));
}
__device__ __forceinline__ float tanhf_fast(float v) {
    return 1.0f - 2.0f * __builtin_amdgcn_rcpf(1.0f + __builtin_amdgcn_exp2f(2.8853900817779268f * v));
}

__global__ __launch_bounds__(512, 2)
void lstm_persist(const float* __restrict__ x,
                  const float* __restrict__ W_ih,
                  const float* __restrict__ W_hh,
                  const float* __restrict__ b_ih,
                  const float* __restrict__ b_hh,
                  const float* __restrict__ W_out,
                  const float* __restrict__ b_out,
                  float* __restrict__ pred) {
    __shared__ short sh[2 * BUFELEMS];

    const int tid  = (int)threadIdx.x;
    const int wave = tid >> 6;           // 0..7
    const int lane = tid & 63;
    const int quad = lane >> 4;          // 0..3
    const int l15  = lane & 15;
    const int n0   = (int)blockIdx.x * 16;

    // ---- weights into bf16 register fragments ----
    // B-frag (16x16x32): lane holds B[k=quad*8+j][n=l15].
    // wave w owns gate j-slice [w*16,w*16+16): wx = W_ih (xg part), wh = W_hh (recurrent).
    short8 wx[4][4], wh[4][4], wo[4];
    float  biasv[4];
#pragma unroll
    for (int t = 0; t < 4; ++t) {
        const int g = t * 128 + wave * 16 + l15;
#pragma unroll
        for (int kk = 0; kk < 4; ++kk) {
            wx[t][kk] = pack8(W_ih + g * H_DIM + kk * 32 + quad * 8);
            wh[t][kk] = pack8(W_hh + g * H_DIM + kk * 32 + quad * 8);
        }
        biasv[t] = b_ih[g] + b_hh[g];
    }
    const int ocol = wave * 16 + l15;
#pragma unroll
    for (int kk = 0; kk < 4; ++kk)
        wo[kk] = pack8(W_out + ocol * H_DIM + kk * 32 + quad * 8);
    const float bo = b_out[ocol];

    // x loader: all 512 threads, one float4 each (16 rows x 128 cols)
    const int xm = tid >> 5;             // row 0..15
    const int xq = (tid & 31) * 4;       // col 0..124 step 4

    // ---- prologue ----
    // zero h region of buf0 (h_{-1} = 0)
    for (int i = tid; i < 16 * 128; i += 512)
        sh[(i >> 7) * ROWP + 128 + (i & 127)] = 0;
    {   // stage x_0 -> buf1 x-region (for xg_0), x_1 -> buf0 x-region (for xg_1 at step 0)
        float4 f0 = *reinterpret_cast<const float4*>(x + ((size_t)(n0 + xm)) * H_DIM + xq);
        float4 f1 = *reinterpret_cast<const float4*>(x + ((size_t)N_BATCH + n0 + xm) * H_DIM + xq);
        *reinterpret_cast<short4v*>(&sh[BUFELEMS + xm * ROWP + xq]) = pack4(f0);
        *reinterpret_cast<short4v*>(&sh[xm * ROWP + xq]) = pack4(f1);
    }
    // register prefetch pipeline: xcur = x_2 (staged at step 0), xnext = x_3
    float4 xcur = *reinterpret_cast<const float4*>(x + ((size_t)2 * N_BATCH + n0 + xm) * H_DIM + xq);
    float4 xnext = *reinterpret_cast<const float4*>(x + ((size_t)3 * N_BATCH + n0 + xm) * H_DIM + xq);
    __syncthreads();

    const int arow = l15 * ROWP + quad * 8;   // a-frag base: A[m=l15][k=quad*8+..]
    const int hcol = 128 + wave * 16 + l15;

    // xg_0 from buf1 x-region
    floatx4 xg0 = {biasv[0], biasv[0], biasv[0], biasv[0]};
    floatx4 xg1 = {biasv[1], biasv[1], biasv[1], biasv[1]};
    floatx4 xg2 = {biasv[2], biasv[2], biasv[2], biasv[2]};
    floatx4 xg3 = {biasv[3], biasv[3], biasv[3], biasv[3]};
#pragma unroll
    for (int kk = 0; kk < 4; ++kk) {
        short8 a = *reinterpret_cast<const short8*>(&sh[BUFELEMS + arow + kk * 32]);
        xg0 = __builtin_amdgcn_mfma_f32_16x16x32_bf16(a, wx[0][kk], xg0, 0, 0, 0);
        xg1 = __builtin_amdgcn_mfma_f32_16x16x32_bf16(a, wx[1][kk], xg1, 0, 0, 0);
        xg2 = __builtin_amdgcn_mfma_f32_16x16x32_bf16(a, wx[2][kk], xg2, 0, 0, 0);
        xg3 = __builtin_amdgcn_mfma_f32_16x16x32_bf16(a, wx[3][kk], xg3, 0, 0, 0);
    }
    __syncthreads();   // buf1-x reads done before step 0 writes x_2 there

    float cc[4] = {0.f, 0.f, 0.f, 0.f};  // cell: c[m=quad*4+r][j=wave*16+l15]

    // ---- main recurrence. Buffer B_s = buf[s&1] holds [x_{s+1} | h_{s-1}]. ----
    for (int s = 0; s < S_LEN; ++s) {
        short* shb = sh + (s & 1) * BUFELEMS;
        short* shn = sh + ((s & 1) ^ 1) * BUFELEMS;

        // gate accs seeded by pipelined xg_s; ao = out-proj of h_{s-1}
        floatx4 g0 = xg0, g1 = xg1, g2 = xg2, g3 = xg3;
        floatx4 ao = {bo, bo, bo, bo};

        // ---- critical path: h_{s-1} part (K=128, 4-deep chains) ----
#pragma unroll
        for (int kk = 0; kk < 4; ++kk) {
            short8 ah = *reinterpret_cast<const short8*>(&shb[arow + 128 + kk * 32]);
            g0 = __builtin_amdgcn_mfma_f32_16x16x32_bf16(ah, wh[0][kk], g0, 0, 0, 0);
            g1 = __builtin_amdgcn_mfma_f32_16x16x32_bf16(ah, wh[1][kk], g1, 0, 0, 0);
            g2 = __builtin_amdgcn_mfma_f32_16x16x32_bf16(ah, wh[2][kk], g2, 0, 0, 0);
            g3 = __builtin_amdgcn_mfma_f32_16x16x32_bf16(ah, wh[3][kk], g3, 0, 0, 0);
            ao = __builtin_amdgcn_mfma_f32_16x16x32_bf16(ah, wo[kk], ao, 0, 0, 0);
        }

        // pred_{s-1}: issue early so the store drain overlaps the rest of the step
        if (s > 0) {
            size_t base = ((size_t)(s - 1) * N_BATCH + n0 + quad * 4) * O_DIM + wave * 16 + l15;
#pragma unroll
            for (int r = 0; r < 4; ++r)
                pred[base + (size_t)r * O_DIM] = ao[r];
        }

        // ---- off-path: xg_{s+1} from x-region of B_s ----
        xg0 = floatx4{biasv[0], biasv[0], biasv[0], biasv[0]};
        xg1 = floatx4{biasv[1], biasv[1], biasv[1], biasv[1]};
        xg2 = floatx4{biasv[2], biasv[2], biasv[2], biasv[2]};
        xg3 = floatx4{biasv[3], biasv[3], biasv[3], biasv[3]};
#pragma unroll
        for (int kk = 0; kk < 4; ++kk) {
            short8 axv = *reinterpret_cast<const short8*>(&shb[arow + kk * 32]);
            xg0 = __builtin_amdgcn_mfma_f32_16x16x32_bf16(axv, wx[0][kk], xg0, 0, 0, 0);
            xg1 = __builtin_amdgcn_mfma_f32_16x16x32_bf16(axv, wx[1][kk], xg1, 0, 0, 0);
            xg2 = __builtin_amdgcn_mfma_f32_16x16x32_bf16(axv, wx[2][kk], xg2, 0, 0, 0);
            xg3 = __builtin_amdgcn_mfma_f32_16x16x32_bf16(axv, wx[3][kk], xg3, 0, 0, 0);
        }

        // stage x_{s+2} (xcur) into B_{s+1}; refill xnext with x_{s+3}
        if (s <= 125)
            *reinterpret_cast<short4v*>(&shn[xm * ROWP + xq]) = pack4(xcur);
        if (s <= 124)
            xnext = *reinterpret_cast<const float4*>(
                x + ((size_t)(s + 3) * N_BATCH + n0 + xm) * H_DIM + xq);

        // ---- activations + state update (D: row m=quad*4+r, col j=wave*16+l15) ----
        float hv[4];
#pragma unroll
        for (int r = 0; r < 4; ++r) {
            float iv = sigmoidf_fast(g0[r]);
            float fv = sigmoidf_fast(g1[r]);
            float gv = tanhf_fast(g2[r]);
            float ov = sigmoidf_fast(g3[r]);
            cc[r] = fv * cc[r] + iv * gv;
            hv[r] = ov * tanhf_fast(cc[r]);
        }
#pragma unroll
        for (int r = 0; r < 4; ++r)
            shn[(quad * 4 + r) * ROWP + hcol] = (short)f2b(hv[r]);

        xcur = xnext;
        __syncthreads();
    }

    // ---- epilogue: pred_{S-1} from h_127 in B_128 = buf0 ----
    floatx4 ao = {bo, bo, bo, bo};
#pragma unroll
    for (int kk = 0; kk < 4; ++kk) {
        short8 ah = *reinterpret_cast<const short8*>(&sh[arow + 128 + kk * 32]);
        ao = __builtin_amdgcn_mfma_f32_16x16x32_bf16(ah, wo[kk], ao, 0, 0, 0);
    }
    size_t base = ((size_t)(S_LEN - 1) * N_BATCH + n0 + quad * 4) * O_DIM + wave * 16 + l15;
#pragma unroll
    for (int r = 0; r < 4; ++r)
        pred[base + (size_t)r * O_DIM] = ao[r];
}

extern "C" void kernel_launch(void* const* d_in, const int* in_sizes, int n_in,
                              void* d_out, int out_size, void* d_ws, size_t ws_size,
                              hipStream_t stream) {
    const float* x    = (const float*)d_in[0];
    const float* Wih  = (const float*)d_in[1];
    const float* Whh  = (const float*)d_in[2];
    const float* bih  = (const float*)d_in[3];
    const float* bhh  = (const float*)d_in[4];
    const float* Wout = (const float*)d_in[5];
    const float* bout = (const float*)d_in[6];
    float* pred = (float*)d_out;

    lstm_persist<<<dim3(N_BATCH / 16), dim3(512), 0, stream>>>(
        x, Wih, Whh, bih, bhh, Wout, bout, pred);
}